// Round 4
// baseline (266.498 us; speedup 1.0000x reference)
//
#include <hip/hip_runtime.h>
#include <hip/hip_bf16.h>
#include <math.h>

#define ALPHA_LEAKY 0.2f
#define EPS_F 1e-10f

// ---------------- degree count ----------------
__global__ void k_count(const int* __restrict__ ei, int* __restrict__ deg, int E) {
    int e = blockIdx.x * blockDim.x + threadIdx.x;
    if (e < E) atomicAdd(&deg[ei[E + e]], 1);
}

// ---------------- linear + per-node scores ----------------
// h = X @ W^T (bf16 out), s_src/s_tgt fused (fp32). Lane = out dim, wave = 8
// rows. W staged in LDS k-major as [32][64] float4: the lane-varying read
// Wl4[k0*64+o] is lane-consecutive (minimum inherent b128 banking). X reads
// are wave-uniform float4 -> HW broadcast, no LDS needed. Grid-stride tiles:
// W staged once per block. LDS 32 KB -> 5 blocks/CU.
__global__ __launch_bounds__(256) void k_linear(
    const float* __restrict__ X, const float* __restrict__ W,
    const float* __restrict__ a, __hip_bfloat16* __restrict__ hb,
    float* __restrict__ s_src, float* __restrict__ s_tgt, int n, int ntiles) {
    __shared__ float4 Wl4[32 * 64];
    const int t = threadIdx.x;
    {
        const float4* W4 = (const float4*)W;   // [64][32] float4
        for (int i = t; i < 2048; i += 256) {
            int o = i >> 5, c = i & 31;
            Wl4[c * 64 + o] = W4[i];
        }
    }
    __syncthreads();

    const int o = t & 63, rq = t >> 6;
    const float a_s = a[o], a_t = a[64 + o];

    for (int tile = blockIdx.x; tile < ntiles; tile += gridDim.x) {
        const int r0 = tile * 32 + rq * 8;
        const float4* xr[8];
        #pragma unroll
        for (int j = 0; j < 8; ++j) {
            int row = r0 + j;
            if (row >= n) row = n - 1;            // clamp; result discarded
            xr[j] = (const float4*)X + (size_t)row * 32;
        }
        float acc[8] = {0.f, 0.f, 0.f, 0.f, 0.f, 0.f, 0.f, 0.f};
        for (int k0 = 0; k0 < 32; ++k0) {
            float4 wv = Wl4[k0 * 64 + o];
            #pragma unroll
            for (int j = 0; j < 8; ++j) {
                float4 xv = xr[j][k0];            // wave-uniform -> broadcast
                acc[j] = fmaf(xv.x, wv.x, acc[j]);
                acc[j] = fmaf(xv.y, wv.y, acc[j]);
                acc[j] = fmaf(xv.z, wv.z, acc[j]);
                acc[j] = fmaf(xv.w, wv.w, acc[j]);
            }
        }
        #pragma unroll
        for (int j = 0; j < 8; ++j) {
            int row = r0 + j;
            if (row < n) hb[(size_t)row * 64 + o] = __float2bfloat16(acc[j]);
            float p = acc[j] * a_s;
            float q = acc[j] * a_t;
            #pragma unroll
            for (int off = 32; off > 0; off >>= 1) {
                p += __shfl_xor(p, off, 64);
                q += __shfl_xor(q, off, 64);
            }
            if (o == 0 && row < n) { s_src[row] = p; s_tgt[row] = q; }
        }
    }
}

// ---------------- CSR segment assignment ----------------
__global__ void k_assign(const int* __restrict__ deg, int* __restrict__ gcur,
                         int* __restrict__ base, int* __restrict__ cursor, int n) {
    int i = blockIdx.x * blockDim.x + threadIdx.x;
    int lane = threadIdx.x & 63;
    int v = (i < n) ? deg[i] : 0;
    int pre = v;
    #pragma unroll
    for (int off = 1; off < 64; off <<= 1) {
        int tt = __shfl_up(pre, off, 64);
        if (lane >= off) pre += tt;
    }
    int total = __shfl(pre, 63, 64);
    int bw = 0;
    if (lane == 63) bw = atomicAdd(gcur, total);
    bw = __shfl(bw, 63, 64);
    int b = bw + pre - v;
    if (i < n) { base[i] = b; cursor[i] = b; }
}

// ---------------- scatter src indices into CSR order ----------------
__global__ void k_scatter(const int* __restrict__ ei, int* __restrict__ cursor,
                          int* __restrict__ csr_src, int E) {
    int e = blockIdx.x * blockDim.x + threadIdx.x;
    if (e >= E) return;
    int s = ei[e];
    int t = ei[E + e];
    int pos = atomicAdd(&cursor[t], 1);
    csr_src[pos] = s;
}

// ---------------- per-node softmax + aggregation + ELU ----------------
// One wave per node. Lane = (group g=lane>>3, r=lane&7). Each step processes
// 8 edges: group g reads source-row (128 B bf16) as one uint4 (16 B/lane x 8
// lanes); lane r covers dims 8r..8r+7 in 8 fp32 accumulators.
__device__ __forceinline__ void accum8(float acc[8], uint4 hv, float w) {
    unsigned u[4] = {hv.x, hv.y, hv.z, hv.w};
    #pragma unroll
    for (int i = 0; i < 4; ++i) {
        float lo = __uint_as_float(u[i] << 16);
        float hi = __uint_as_float(u[i] & 0xFFFF0000u);
        acc[2 * i]     = fmaf(w, lo, acc[2 * i]);
        acc[2 * i + 1] = fmaf(w, hi, acc[2 * i + 1]);
    }
}

__global__ __launch_bounds__(256) void k_node(
    const int* __restrict__ base, const int* __restrict__ deg,
    const int* __restrict__ csr_src, const float* __restrict__ s_src,
    const float* __restrict__ s_tgt, const __hip_bfloat16* __restrict__ hb,
    float* __restrict__ out, int n) {
    const int lane = threadIdx.x & 63;
    const int node = blockIdx.x * 4 + (threadIdx.x >> 6);
    if (node >= n) return;
    const int b = base[node];
    const int d = deg[node];
    const float st = s_tgt[node];
    const int g = lane >> 3, r = lane & 7;
    float acc[8] = {0.f, 0.f, 0.f, 0.f, 0.f, 0.f, 0.f, 0.f};

    if (d <= 64) {
        int src_l = 0; float w_l = 0.f, v = -INFINITY;
        if (lane < d) {
            src_l = csr_src[b + lane];
            float x = s_src[src_l] + st;
            v = (x > 0.f) ? x : ALPHA_LEAKY * x;
        }
        float m = v;
        #pragma unroll
        for (int off = 32; off > 0; off >>= 1) m = fmaxf(m, __shfl_xor(m, off, 64));
        float ex = (lane < d) ? expf(v - m) : 0.f;
        float sum = ex;
        #pragma unroll
        for (int off = 32; off > 0; off >>= 1) sum += __shfl_xor(sum, off, 64);
        w_l = ex * (1.f / (sum + EPS_F));
        for (int k = 0; k < d; k += 8) {
            int ke = k + g;                       // <= 63, in shfl range
            int s    = __shfl(src_l, ke, 64);     // src=0 / w=0 beyond d
            float w  = __shfl(w_l,  ke, 64);
            uint4 hv = ((const uint4*)(hb + (size_t)s * 64))[r];
            accum8(acc, hv, w);
        }
    } else {
        float m = -INFINITY;
        for (int c = lane; c < d; c += 64) {
            float x = s_src[csr_src[b + c]] + st;
            x = (x > 0.f) ? x : ALPHA_LEAKY * x;
            m = fmaxf(m, x);
        }
        #pragma unroll
        for (int off = 32; off > 0; off >>= 1) m = fmaxf(m, __shfl_xor(m, off, 64));
        float sum = 0.f;
        for (int c = lane; c < d; c += 64) {
            float x = s_src[csr_src[b + c]] + st;
            x = (x > 0.f) ? x : ALPHA_LEAKY * x;
            sum += expf(x - m);
        }
        #pragma unroll
        for (int off = 32; off > 0; off >>= 1) sum += __shfl_xor(sum, off, 64);
        float inv = 1.f / (sum + EPS_F);
        for (int c0 = 0; c0 < d; c0 += 64) {
            int j = c0 + lane;
            int src_l = 0; float w_l = 0.f;
            if (j < d) {
                src_l = csr_src[b + j];
                float x = s_src[src_l] + st;
                x = (x > 0.f) ? x : ALPHA_LEAKY * x;
                w_l = expf(x - m) * inv;
            }
            int lim = min(64, d - c0);
            for (int k = 0; k < lim; k += 8) {
                int ke = k + g;
                int s    = __shfl(src_l, ke, 64);
                float w  = __shfl(w_l,  ke, 64);
                uint4 hv = ((const uint4*)(hb + (size_t)s * 64))[r];
                accum8(acc, hv, w);
            }
        }
    }

    // reduce the 8 groups (lanes r, r+8, ..., r+56 hold dims 8r..8r+7)
    #pragma unroll
    for (int off = 8; off <= 32; off <<= 1) {
        #pragma unroll
        for (int j = 0; j < 8; ++j) acc[j] += __shfl_xor(acc[j], off, 64);
    }
    if (g == 0) {
        float4 o0, o1;
        o0.x = acc[0] > 0.f ? acc[0] : expf(acc[0]) - 1.f;
        o0.y = acc[1] > 0.f ? acc[1] : expf(acc[1]) - 1.f;
        o0.z = acc[2] > 0.f ? acc[2] : expf(acc[2]) - 1.f;
        o0.w = acc[3] > 0.f ? acc[3] : expf(acc[3]) - 1.f;
        o1.x = acc[4] > 0.f ? acc[4] : expf(acc[4]) - 1.f;
        o1.y = acc[5] > 0.f ? acc[5] : expf(acc[5]) - 1.f;
        o1.z = acc[6] > 0.f ? acc[6] : expf(acc[6]) - 1.f;
        o1.w = acc[7] > 0.f ? acc[7] : expf(acc[7]) - 1.f;
        float4* o4 = (float4*)out + (size_t)node * 16;
        o4[r * 2]     = o0;
        o4[r * 2 + 1] = o1;
    }
}

extern "C" void kernel_launch(void* const* d_in, const int* in_sizes, int n_in,
                              void* d_out, int out_size, void* d_ws, size_t ws_size,
                              hipStream_t stream) {
    const float* X  = (const float*)d_in[0];   // [N,128]
    const int*   ei = (const int*)d_in[1];     // [2,E]
    const float* W  = (const float*)d_in[2];   // [64,128]
    const float* a  = (const float*)d_in[3];   // [1,128]
    float* out = (float*)d_out;                // [N,64]

    const int N = in_sizes[0] / 128;
    const int E = in_sizes[1] / 2;

    char* p = (char*)d_ws;
    __hip_bfloat16* hb = (__hip_bfloat16*)p; p += (size_t)N * 64 * sizeof(__hip_bfloat16);
    float* s_src  = (float*)p;  p += (size_t)N * sizeof(float);
    float* s_tgt  = (float*)p;  p += (size_t)N * sizeof(float);
    int*   deg    = (int*)p;    p += (size_t)N * sizeof(int);
    int*   gcur   = (int*)p;    p += sizeof(int);          // adjacent to deg
    int*   base   = (int*)p;    p += (size_t)N * sizeof(int);
    int*   cursor = (int*)p;    p += (size_t)N * sizeof(int);
    int*   csr_src= (int*)p;

    hipMemsetAsync(deg, 0, (size_t)(N + 1) * sizeof(int), stream);  // deg + gcur

    const int ntiles = (N + 31) / 32;
    k_count  <<<(E + 255) / 256, 256, 0, stream>>>(ei, deg, E);
    k_linear <<<1280,            256, 0, stream>>>(X, W, a, hb, s_src, s_tgt, N, ntiles);
    k_assign <<<(N + 255) / 256, 256, 0, stream>>>(deg, gcur, base, cursor, N);
    k_scatter<<<(E + 255) / 256, 256, 0, stream>>>(ei, cursor, csr_src, E);
    k_node   <<<(N + 3) / 4,     256, 0, stream>>>(base, deg, csr_src, s_src, s_tgt, hb, out, N);
}

// Round 7
// 223.076 us; speedup vs baseline: 1.1946x; 1.1946x over previous
//
#include <hip/hip_runtime.h>
#include <math.h>

#define ALPHA_LEAKY 0.2f
#define EPS_F 1e-10f

typedef __attribute__((ext_vector_type(8))) short short8;   // 8 bf16 (4 VGPRs)
typedef __attribute__((ext_vector_type(4))) float f32x4;    // MFMA C/D frag

__device__ __forceinline__ unsigned short bf16_rne(float f) {
    unsigned u = __float_as_uint(f);
    u += 0x7FFFu + ((u >> 16) & 1u);
    return (unsigned short)(u >> 16);
}

// prep: W -> MFMA B-frags (bf16), w_s/w_t = W^T a
// Wbf frag f = (nt*4+kt)*64 + lane; elem j = W[nt*16+(lane&15)][kt*32+(lane>>4)*8+j]
__global__ void k_prep(const float* __restrict__ W, const float* __restrict__ a,
                       uint4* __restrict__ Wbf, float* __restrict__ w_s,
                       float* __restrict__ w_t) {
    if (blockIdx.x < 16) {
        int f = blockIdx.x * 256 + threadIdx.x;
        int nt = f >> 8;
        if (nt >= 4) return;                  // only 1024 valid frags
        int l = f & 63, kt = (f >> 6) & 3;
        int nn = nt * 16 + (l & 15);
        int k  = kt * 32 + (l >> 4) * 8;
        const float* wr = W + nn * 128 + k;
        unsigned short b[8];
        #pragma unroll
        for (int j = 0; j < 8; ++j) b[j] = bf16_rne(wr[j]);
        uint4 v;
        v.x = (unsigned)b[0] | ((unsigned)b[1] << 16);
        v.y = (unsigned)b[2] | ((unsigned)b[3] << 16);
        v.z = (unsigned)b[4] | ((unsigned)b[5] << 16);
        v.w = (unsigned)b[6] | ((unsigned)b[7] << 16);
        Wbf[f] = v;
    } else {
        int k = threadIdx.x;
        if (k < 128) {
            float ps = 0.f, pt = 0.f;
            for (int nn = 0; nn < 64; ++nn) {
                float wv = W[nn * 128 + k];
                ps += wv * a[nn];
                pt += wv * a[64 + nn];
            }
            w_s[k] = ps;
            w_t[k] = pt;
        }
    }
}

// fused: degree count + fp32 scores. Count atomics are fire-and-forget and
// overlap the streaming score pass (no LDS, no barriers). Wave = 2 rows,
// (lane&31) = k-chunk of 4 floats, w_s/w_t held in registers.
__global__ __launch_bounds__(256) void k_aux(
    const float* __restrict__ X, const int* __restrict__ ei,
    const float* __restrict__ w_s, const float* __restrict__ w_t,
    int* __restrict__ deg, float* __restrict__ s_src, float* __restrict__ s_tgt,
    int n, int E) {
    const int gsize = gridDim.x * 256;
    const int gtid  = blockIdx.x * 256 + threadIdx.x;
    for (int e = gtid; e < E; e += gsize) atomicAdd(&deg[ei[E + e]], 1);

    const int lane = threadIdx.x & 63;
    const int k4   = lane & 31;
    float4 ws4 = ((const float4*)w_s)[k4];
    float4 wt4 = ((const float4*)w_t)[k4];
    const int nwaves = gridDim.x * 4;
    const int wid    = blockIdx.x * 4 + (threadIdx.x >> 6);
    const int npairs = (n + 1) >> 1;
    for (int rp = wid; rp < npairs; rp += nwaves) {
        int row = rp * 2 + (lane >> 5);
        int rr  = min(row, n - 1);
        float4 xv = ((const float4*)X)[(size_t)rr * 32 + k4];
        float p = xv.x * ws4.x + xv.y * ws4.y + xv.z * ws4.z + xv.w * ws4.w;
        float q = xv.x * wt4.x + xv.y * wt4.y + xv.z * wt4.z + xv.w * wt4.w;
        #pragma unroll
        for (int off = 16; off > 0; off >>= 1) {
            p += __shfl_xor(p, off, 64);
            q += __shfl_xor(q, off, 64);
        }
        if (k4 == 0 && row < n) { s_src[row] = p; s_tgt[row] = q; }
    }
}

// MFMA GEMM: h = bf16(X) @ bf16(W)^T. One wave per 16-row stripe. All of W
// (64x128) pinned as B-frags in 64 VGPRs; A-frags read straight from fp32 X
// (16 full 128B lines per stripe), converted in-register. No LDS.
// C/D map: col = lane&15, row = (lane>>4)*4 + reg  (measured m89/m91).
__global__ __launch_bounds__(256) void k_gemm(
    const float* __restrict__ X, const uint4* __restrict__ Wbf,
    unsigned short* __restrict__ hb, int n, int nstripes) {
    const int lane = threadIdx.x & 63;
    const int ml = lane & 15, g = lane >> 4;
    short8 bfr[4][4];
    #pragma unroll
    for (int nt = 0; nt < 4; ++nt)
        #pragma unroll
        for (int kt = 0; kt < 4; ++kt) {
            uint4 v = Wbf[(nt * 4 + kt) * 64 + lane];
            bfr[nt][kt] = *(short8*)&v;
        }
    for (int stripe = blockIdx.x * 4 + (threadIdx.x >> 6); stripe < nstripes;
         stripe += gridDim.x * 4) {
        const int row0 = stripe * 16;
        const int rrow = min(row0 + ml, n - 1);   // clamp; dup rows harmless
        const float* xr = X + (size_t)rrow * 128;
        f32x4 acc[4] = {{0.f,0.f,0.f,0.f},{0.f,0.f,0.f,0.f},
                        {0.f,0.f,0.f,0.f},{0.f,0.f,0.f,0.f}};
        #pragma unroll
        for (int kt = 0; kt < 4; ++kt) {
            float4 x0 = *(const float4*)(xr + kt * 32 + g * 8);
            float4 x1 = *(const float4*)(xr + kt * 32 + g * 8 + 4);
            short8 af;
            af[0] = (short)bf16_rne(x0.x); af[1] = (short)bf16_rne(x0.y);
            af[2] = (short)bf16_rne(x0.z); af[3] = (short)bf16_rne(x0.w);
            af[4] = (short)bf16_rne(x1.x); af[5] = (short)bf16_rne(x1.y);
            af[6] = (short)bf16_rne(x1.z); af[7] = (short)bf16_rne(x1.w);
            #pragma unroll
            for (int nt = 0; nt < 4; ++nt)
                acc[nt] = __builtin_amdgcn_mfma_f32_16x16x32_bf16(
                    af, bfr[nt][kt], acc[nt], 0, 0, 0);
        }
        #pragma unroll
        for (int nt = 0; nt < 4; ++nt)
            #pragma unroll
            for (int reg = 0; reg < 4; ++reg) {
                int row = row0 + g * 4 + reg;
                if (row < n)
                    hb[(size_t)row * 64 + nt * 16 + ml] = bf16_rne(acc[nt][reg]);
            }
    }
}

// CSR segment assignment: wave-level scan over deg, one global-cursor atomic
// per wave. Placement order nondeterministic but contiguous/disjoint.
__global__ void k_assign(const int* __restrict__ deg, int* __restrict__ gcur,
                         int* __restrict__ base, int* __restrict__ cursor, int n) {
    int i = blockIdx.x * blockDim.x + threadIdx.x;
    int lane = threadIdx.x & 63;
    int v = (i < n) ? deg[i] : 0;
    int pre = v;
    #pragma unroll
    for (int off = 1; off < 64; off <<= 1) {
        int tt = __shfl_up(pre, off, 64);
        if (lane >= off) pre += tt;
    }
    int total = __shfl(pre, 63, 64);
    int bw = 0;
    if (lane == 63) bw = atomicAdd(gcur, total);
    bw = __shfl(bw, 63, 64);
    int b = bw + pre - v;
    if (i < n) { base[i] = b; cursor[i] = b; }
}

// scatter src indices into CSR order
__global__ void k_scatter(const int* __restrict__ ei, int* __restrict__ cursor,
                          int* __restrict__ csr_src, int E) {
    int e = blockIdx.x * blockDim.x + threadIdx.x;
    if (e >= E) return;
    int s = ei[e];
    int t = ei[E + e];
    int pos = atomicAdd(&cursor[t], 1);
    csr_src[pos] = s;
}

// per-node softmax + aggregation + ELU. One wave per node. Lane = (group
// g=lane>>3, r=lane&7); each step processes 8 edges: group g reads its
// source row (128 B bf16) as one uint4 per lane; lane r covers dims 8r..8r+7.
__device__ __forceinline__ void accum8(float acc[8], uint4 hv, float w) {
    unsigned u[4] = {hv.x, hv.y, hv.z, hv.w};
    #pragma unroll
    for (int i = 0; i < 4; ++i) {
        float lo = __uint_as_float(u[i] << 16);
        float hi = __uint_as_float(u[i] & 0xFFFF0000u);
        acc[2 * i]     = fmaf(w, lo, acc[2 * i]);
        acc[2 * i + 1] = fmaf(w, hi, acc[2 * i + 1]);
    }
}

__global__ __launch_bounds__(256) void k_node(
    const int* __restrict__ base, const int* __restrict__ deg,
    const int* __restrict__ csr_src, const float* __restrict__ s_src,
    const float* __restrict__ s_tgt, const unsigned short* __restrict__ hb,
    float* __restrict__ out, int n) {
    const int lane = threadIdx.x & 63;
    const int node = blockIdx.x * 4 + (threadIdx.x >> 6);
    if (node >= n) return;
    const int b = base[node];
    const int d = deg[node];
    const float st = s_tgt[node];
    const int g = lane >> 3, r = lane & 7;
    float acc[8] = {0.f, 0.f, 0.f, 0.f, 0.f, 0.f, 0.f, 0.f};

    if (d <= 64) {
        int src_l = 0; float w_l = 0.f, v = -INFINITY;
        if (lane < d) {
            src_l = csr_src[b + lane];
            float x = s_src[src_l] + st;
            v = (x > 0.f) ? x : ALPHA_LEAKY * x;
        }
        float m = v;
        #pragma unroll
        for (int off = 32; off > 0; off >>= 1) m = fmaxf(m, __shfl_xor(m, off, 64));
        float ex = (lane < d) ? expf(v - m) : 0.f;
        float sum = ex;
        #pragma unroll
        for (int off = 32; off > 0; off >>= 1) sum += __shfl_xor(sum, off, 64);
        w_l = ex * (1.f / (sum + EPS_F));
        for (int k = 0; k < d; k += 8) {
            int ke = k + g;                       // <= 63, in shfl range
            int s   = __shfl(src_l, ke, 64);      // src=0 / w=0 beyond d
            float w = __shfl(w_l,  ke, 64);
            uint4 hv = ((const uint4*)(hb + (size_t)s * 64))[r];
            accum8(acc, hv, w);
        }
    } else {
        float m = -INFINITY;
        for (int c = lane; c < d; c += 64) {
            float x = s_src[csr_src[b + c]] + st;
            x = (x > 0.f) ? x : ALPHA_LEAKY * x;
            m = fmaxf(m, x);
        }
        #pragma unroll
        for (int off = 32; off > 0; off >>= 1) m = fmaxf(m, __shfl_xor(m, off, 64));
        float sum = 0.f;
        for (int c = lane; c < d; c += 64) {
            float x = s_src[csr_src[b + c]] + st;
            x = (x > 0.f) ? x : ALPHA_LEAKY * x;
            sum += expf(x - m);
        }
        #pragma unroll
        for (int off = 32; off > 0; off >>= 1) sum += __shfl_xor(sum, off, 64);
        float inv = 1.f / (sum + EPS_F);
        for (int c0 = 0; c0 < d; c0 += 64) {
            int j = c0 + lane;
            int src_l = 0; float w_l = 0.f;
            if (j < d) {
                src_l = csr_src[b + j];
                float x = s_src[src_l] + st;
                x = (x > 0.f) ? x : ALPHA_LEAKY * x;
                w_l = expf(x - m) * inv;
            }
            int lim = min(64, d - c0);
            for (int k = 0; k < lim; k += 8) {
                int ke = k + g;
                int s   = __shfl(src_l, ke, 64);
                float w = __shfl(w_l,  ke, 64);
                uint4 hv = ((const uint4*)(hb + (size_t)s * 64))[r];
                accum8(acc, hv, w);
            }
        }
    }

    // reduce the 8 groups (lanes r, r+8, ..., r+56 hold dims 8r..8r+7)
    #pragma unroll
    for (int off = 8; off <= 32; off <<= 1) {
        #pragma unroll
        for (int j = 0; j < 8; ++j) acc[j] += __shfl_xor(acc[j], off, 64);
    }
    if (g == 0) {
        float4 o0, o1;
        o0.x = acc[0] > 0.f ? acc[0] : expf(acc[0]) - 1.f;
        o0.y = acc[1] > 0.f ? acc[1] : expf(acc[1]) - 1.f;
        o0.z = acc[2] > 0.f ? acc[2] : expf(acc[2]) - 1.f;
        o0.w = acc[3] > 0.f ? acc[3] : expf(acc[3]) - 1.f;
        o1.x = acc[4] > 0.f ? acc[4] : expf(acc[4]) - 1.f;
        o1.y = acc[5] > 0.f ? acc[5] : expf(acc[5]) - 1.f;
        o1.z = acc[6] > 0.f ? acc[6] : expf(acc[6]) - 1.f;
        o1.w = acc[7] > 0.f ? acc[7] : expf(acc[7]) - 1.f;
        float4* o4 = (float4*)out + (size_t)node * 16;
        o4[r * 2]     = o0;
        o4[r * 2 + 1] = o1;
    }
}

extern "C" void kernel_launch(void* const* d_in, const int* in_sizes, int n_in,
                              void* d_out, int out_size, void* d_ws, size_t ws_size,
                              hipStream_t stream) {
    const float* X  = (const float*)d_in[0];   // [N,128]
    const int*   ei = (const int*)d_in[1];     // [2,E]
    const float* W  = (const float*)d_in[2];   // [64,128]
    const float* a  = (const float*)d_in[3];   // [1,128]
    float* out = (float*)d_out;                // [N,64]

    const int N = in_sizes[0] / 128;
    const int E = in_sizes[1] / 2;

    char* p = (char*)d_ws;
    unsigned short* hb = (unsigned short*)p; p += (size_t)N * 64 * sizeof(unsigned short);
    uint4* Wbf    = (uint4*)p;  p += 1024 * sizeof(uint4);   // 4nt * 4kt * 64 lanes
    float* w_s    = (float*)p;  p += 128 * sizeof(float);
    float* w_t    = (float*)p;  p += 128 * sizeof(float);
    float* s_src  = (float*)p;  p += (size_t)N * sizeof(float);
    float* s_tgt  = (float*)p;  p += (size_t)N * sizeof(float);
    int*   deg    = (int*)p;    p += (size_t)N * sizeof(int);
    int*   gcur   = (int*)p;    p += sizeof(int);            // adjacent to deg
    int*   base   = (int*)p;    p += (size_t)N * sizeof(int);
    int*   cursor = (int*)p;    p += (size_t)N * sizeof(int);
    int*   csr_src= (int*)p;

    hipMemsetAsync(deg, 0, (size_t)(N + 1) * sizeof(int), stream);  // deg + gcur

    const int nstripes = (N + 15) / 16;
    k_prep   <<<17, 256, 0, stream>>>(W, a, Wbf, w_s, w_t);
    k_aux    <<<1280, 256, 0, stream>>>(X, ei, w_s, w_t, deg, s_src, s_tgt, N, E);
    k_gemm   <<<(nstripes + 3) / 4, 256, 0, stream>>>(X, Wbf, hb, N, nstripes);
    k_assign <<<(N + 255) / 256, 256, 0, stream>>>(deg, gcur, base, cursor, N);
    k_scatter<<<(E + 255) / 256, 256, 0, stream>>>(ei, cursor, csr_src, E);
    k_node   <<<(N + 3) / 4, 256, 0, stream>>>(base, deg, csr_src, s_src, s_tgt, hb, out, N);
}

// Round 8
// 221.610 us; speedup vs baseline: 1.2026x; 1.0066x over previous
//
#include <hip/hip_runtime.h>
#include <math.h>

#define ALPHA_LEAKY 0.2f
#define EPS_F 1e-10f

typedef __attribute__((ext_vector_type(8))) short short8;   // 8 bf16 (4 VGPRs)
typedef __attribute__((ext_vector_type(4))) float f32x4;    // MFMA C/D frag

__device__ __forceinline__ unsigned short bf16_rne(float f) {
    unsigned u = __float_as_uint(f);
    u += 0x7FFFu + ((u >> 16) & 1u);
    return (unsigned short)(u >> 16);
}

// prep: W -> MFMA B-frags (bf16), w_s/w_t = W^T a
__global__ void k_prep(const float* __restrict__ W, const float* __restrict__ a,
                       uint4* __restrict__ Wbf, float* __restrict__ w_s,
                       float* __restrict__ w_t) {
    if (blockIdx.x < 16) {
        int f = blockIdx.x * 256 + threadIdx.x;
        int nt = f >> 8;
        if (nt >= 4) return;                  // only 1024 valid frags
        int l = f & 63, kt = (f >> 6) & 3;
        int nn = nt * 16 + (l & 15);
        int k  = kt * 32 + (l >> 4) * 8;
        const float* wr = W + nn * 128 + k;
        unsigned short b[8];
        #pragma unroll
        for (int j = 0; j < 8; ++j) b[j] = bf16_rne(wr[j]);
        uint4 v;
        v.x = (unsigned)b[0] | ((unsigned)b[1] << 16);
        v.y = (unsigned)b[2] | ((unsigned)b[3] << 16);
        v.z = (unsigned)b[4] | ((unsigned)b[5] << 16);
        v.w = (unsigned)b[6] | ((unsigned)b[7] << 16);
        Wbf[f] = v;
    } else {
        int k = threadIdx.x;
        if (k < 128) {
            float ps = 0.f, pt = 0.f;
            for (int nn = 0; nn < 64; ++nn) {
                float wv = W[nn * 128 + k];
                ps += wv * a[nn];
                pt += wv * a[64 + nn];
            }
            w_s[k] = ps;
            w_t[k] = pt;
        }
    }
}

// fused: bucket count (non-returning atomics to 782 padded hot lines) +
// fp32 scores (s_src = X.w_s, s_tgt = X.w_t; wave = 2 rows).
__global__ __launch_bounds__(256) void k_aux(
    const float* __restrict__ X, const int* __restrict__ ei,
    const float* __restrict__ w_s, const float* __restrict__ w_t,
    int* __restrict__ bcount, float* __restrict__ s_src,
    float* __restrict__ s_tgt, int n, int E) {
    const int gsize = gridDim.x * 256;
    const int gtid  = blockIdx.x * 256 + threadIdx.x;
    for (int e = gtid; e < E; e += gsize)
        atomicAdd(&bcount[(ei[E + e] >> 6) * 16], 1);

    const int lane = threadIdx.x & 63;
    const int k4   = lane & 31;
    float4 ws4 = ((const float4*)w_s)[k4];
    float4 wt4 = ((const float4*)w_t)[k4];
    const int nwaves = gridDim.x * 4;
    const int wid    = blockIdx.x * 4 + (threadIdx.x >> 6);
    const int npairs = (n + 1) >> 1;
    for (int rp = wid; rp < npairs; rp += nwaves) {
        int row = rp * 2 + (lane >> 5);
        int rr  = min(row, n - 1);
        float4 xv = ((const float4*)X)[(size_t)rr * 32 + k4];
        float p = xv.x * ws4.x + xv.y * ws4.y + xv.z * ws4.z + xv.w * ws4.w;
        float q = xv.x * wt4.x + xv.y * wt4.y + xv.z * wt4.z + xv.w * wt4.w;
        #pragma unroll
        for (int off = 16; off > 0; off >>= 1) {
            p += __shfl_xor(p, off, 64);
            q += __shfl_xor(q, off, 64);
        }
        if (k4 == 0 && row < n) { s_src[row] = p; s_tgt[row] = q; }
    }
}

// single-block exclusive scan of bucket counts -> bstart (ordered regions),
// bcur init. Handles nb <= 1024.
__global__ __launch_bounds__(256) void k_bscan(
    const int* __restrict__ bcount, int* __restrict__ bstart,
    int* __restrict__ bcur, int nb, int E) {
    __shared__ int wsum[4];
    int t = threadIdx.x;
    int lane = t & 63, w = t >> 6;
    int v[4]; int sum = 0;
    #pragma unroll
    for (int j = 0; j < 4; ++j) {
        int idx = t * 4 + j;
        v[j] = (idx < nb) ? bcount[idx * 16] : 0;
        sum += v[j];
    }
    int pre = sum;
    #pragma unroll
    for (int off = 1; off < 64; off <<= 1) {
        int x = __shfl_up(pre, off, 64);
        if (lane >= off) pre += x;
    }
    if (lane == 63) wsum[w] = pre;
    __syncthreads();
    int wbase = 0;
    for (int k = 0; k < w; ++k) wbase += wsum[k];
    int run = wbase + pre - sum;     // exclusive prefix for this thread's chunk
    #pragma unroll
    for (int j = 0; j < 4; ++j) {
        int idx = t * 4 + j;
        if (idx < nb) { bstart[idx] = run; bcur[idx * 16] = run; }
        run += v[j];
    }
    if (t == 255) bstart[nb] = E;
}

// phase 1: append (src,tgt) to the target's bucket region. Returning atomics
// hit 782 padded hot lines; staging writes are tail-line coalesced.
__global__ void k_bucket(const int* __restrict__ ei, int* __restrict__ bcur,
                         int2* __restrict__ st, int E) {
    int e = blockIdx.x * blockDim.x + threadIdx.x;
    if (e >= E) return;
    int s = ei[e];
    int t = ei[E + e];
    int pos = atomicAdd(&bcur[(t >> 6) * 16], 1);
    st[pos] = make_int2(s, t);
}

// phase 2: one block per bucket (64 nodes). LDS histogram -> local scan gives
// deterministic base/deg; LDS-cursor placement writes csr_src into the
// bucket's contiguous region. No global atomics.
__global__ __launch_bounds__(256) void k_local(
    const int2* __restrict__ st, const int* __restrict__ bstart,
    int* __restrict__ base, int* __restrict__ deg, int* __restrict__ csr_src,
    int n) {
    __shared__ int hist[64];
    __shared__ int nbase[64];
    const int b = blockIdx.x;
    const int n0 = b << 6;
    const int t = threadIdx.x;
    if (t < 64) hist[t] = 0;
    __syncthreads();
    const int s0 = bstart[b], s1 = bstart[b + 1];
    for (int i = s0 + t; i < s1; i += 256)
        atomicAdd(&hist[st[i].y - n0], 1);
    __syncthreads();
    if (t < 64) {
        int v = hist[t];
        int pre = v;
        #pragma unroll
        for (int off = 1; off < 64; off <<= 1) {
            int x = __shfl_up(pre, off, 64);
            if (t >= off) pre += x;
        }
        int bs = s0 + pre - v;       // exclusive
        nbase[t] = bs;
        if (n0 + t < n) { base[n0 + t] = bs; deg[n0 + t] = v; }
    }
    __syncthreads();
    if (t < 64) hist[t] = nbase[t];  // reuse as cursors
    __syncthreads();
    for (int i = s0 + t; i < s1; i += 256) {
        int2 e = st[i];
        int slot = atomicAdd(&hist[e.y - n0], 1);
        csr_src[slot] = e.x;
    }
}

// MFMA GEMM: h = bf16(X) @ bf16(W)^T. One wave per 16-row stripe; W pinned
// as B-frags in 64 VGPRs; A-frags straight from fp32 X; no LDS.
// C/D map: col = lane&15, row = (lane>>4)*4 + reg.
__global__ __launch_bounds__(256) void k_gemm(
    const float* __restrict__ X, const uint4* __restrict__ Wbf,
    unsigned short* __restrict__ hb, int n, int nstripes) {
    const int lane = threadIdx.x & 63;
    const int ml = lane & 15, g = lane >> 4;
    short8 bfr[4][4];
    #pragma unroll
    for (int nt = 0; nt < 4; ++nt)
        #pragma unroll
        for (int kt = 0; kt < 4; ++kt) {
            uint4 v = Wbf[(nt * 4 + kt) * 64 + lane];
            bfr[nt][kt] = *(short8*)&v;
        }
    for (int stripe = blockIdx.x * 4 + (threadIdx.x >> 6); stripe < nstripes;
         stripe += gridDim.x * 4) {
        const int row0 = stripe * 16;
        const int rrow = min(row0 + ml, n - 1);
        const float* xr = X + (size_t)rrow * 128;
        f32x4 acc[4] = {{0.f,0.f,0.f,0.f},{0.f,0.f,0.f,0.f},
                        {0.f,0.f,0.f,0.f},{0.f,0.f,0.f,0.f}};
        #pragma unroll
        for (int kt = 0; kt < 4; ++kt) {
            float4 x0 = *(const float4*)(xr + kt * 32 + g * 8);
            float4 x1 = *(const float4*)(xr + kt * 32 + g * 8 + 4);
            short8 af;
            af[0] = (short)bf16_rne(x0.x); af[1] = (short)bf16_rne(x0.y);
            af[2] = (short)bf16_rne(x0.z); af[3] = (short)bf16_rne(x0.w);
            af[4] = (short)bf16_rne(x1.x); af[5] = (short)bf16_rne(x1.y);
            af[6] = (short)bf16_rne(x1.z); af[7] = (short)bf16_rne(x1.w);
            #pragma unroll
            for (int nt = 0; nt < 4; ++nt)
                acc[nt] = __builtin_amdgcn_mfma_f32_16x16x32_bf16(
                    af, bfr[nt][kt], acc[nt], 0, 0, 0);
        }
        #pragma unroll
        for (int nt = 0; nt < 4; ++nt)
            #pragma unroll
            for (int reg = 0; reg < 4; ++reg) {
                int row = row0 + g * 4 + reg;
                if (row < n)
                    hb[(size_t)row * 64 + nt * 16 + ml] = bf16_rne(acc[nt][reg]);
            }
    }
}

// per-node softmax + aggregation + ELU (one wave per node; lane = (g,r);
// 8 edges per step, each group reads one 128 B bf16 row as uint4).
__device__ __forceinline__ void accum8(float acc[8], uint4 hv, float w) {
    unsigned u[4] = {hv.x, hv.y, hv.z, hv.w};
    #pragma unroll
    for (int i = 0; i < 4; ++i) {
        float lo = __uint_as_float(u[i] << 16);
        float hi = __uint_as_float(u[i] & 0xFFFF0000u);
        acc[2 * i]     = fmaf(w, lo, acc[2 * i]);
        acc[2 * i + 1] = fmaf(w, hi, acc[2 * i + 1]);
    }
}

__global__ __launch_bounds__(256) void k_node(
    const int* __restrict__ base, const int* __restrict__ deg,
    const int* __restrict__ csr_src, const float* __restrict__ s_src,
    const float* __restrict__ s_tgt, const unsigned short* __restrict__ hb,
    float* __restrict__ out, int n) {
    const int lane = threadIdx.x & 63;
    const int node = blockIdx.x * 4 + (threadIdx.x >> 6);
    if (node >= n) return;
    const int b = base[node];
    const int d = deg[node];
    const float st = s_tgt[node];
    const int g = lane >> 3, r = lane & 7;
    float acc[8] = {0.f, 0.f, 0.f, 0.f, 0.f, 0.f, 0.f, 0.f};

    if (d <= 64) {
        int src_l = 0; float w_l = 0.f, v = -INFINITY;
        if (lane < d) {
            src_l = csr_src[b + lane];
            float x = s_src[src_l] + st;
            v = (x > 0.f) ? x : ALPHA_LEAKY * x;
        }
        float m = v;
        #pragma unroll
        for (int off = 32; off > 0; off >>= 1) m = fmaxf(m, __shfl_xor(m, off, 64));
        float ex = (lane < d) ? expf(v - m) : 0.f;
        float sum = ex;
        #pragma unroll
        for (int off = 32; off > 0; off >>= 1) sum += __shfl_xor(sum, off, 64);
        w_l = ex * (1.f / (sum + EPS_F));
        for (int k = 0; k < d; k += 8) {
            int ke = k + g;
            int s   = __shfl(src_l, ke, 64);
            float w = __shfl(w_l,  ke, 64);
            uint4 hv = ((const uint4*)(hb + (size_t)s * 64))[r];
            accum8(acc, hv, w);
        }
    } else {
        float m = -INFINITY;
        for (int c = lane; c < d; c += 64) {
            float x = s_src[csr_src[b + c]] + st;
            x = (x > 0.f) ? x : ALPHA_LEAKY * x;
            m = fmaxf(m, x);
        }
        #pragma unroll
        for (int off = 32; off > 0; off >>= 1) m = fmaxf(m, __shfl_xor(m, off, 64));
        float sum = 0.f;
        for (int c = lane; c < d; c += 64) {
            float x = s_src[csr_src[b + c]] + st;
            x = (x > 0.f) ? x : ALPHA_LEAKY * x;
            sum += expf(x - m);
        }
        #pragma unroll
        for (int off = 32; off > 0; off >>= 1) sum += __shfl_xor(sum, off, 64);
        float inv = 1.f / (sum + EPS_F);
        for (int c0 = 0; c0 < d; c0 += 64) {
            int j = c0 + lane;
            int src_l = 0; float w_l = 0.f;
            if (j < d) {
                src_l = csr_src[b + j];
                float x = s_src[src_l] + st;
                x = (x > 0.f) ? x : ALPHA_LEAKY * x;
                w_l = expf(x - m) * inv;
            }
            int lim = min(64, d - c0);
            for (int k = 0; k < lim; k += 8) {
                int ke = k + g;
                int s   = __shfl(src_l, ke, 64);
                float w = __shfl(w_l,  ke, 64);
                uint4 hv = ((const uint4*)(hb + (size_t)s * 64))[r];
                accum8(acc, hv, w);
            }
        }
    }

    #pragma unroll
    for (int off = 8; off <= 32; off <<= 1) {
        #pragma unroll
        for (int j = 0; j < 8; ++j) acc[j] += __shfl_xor(acc[j], off, 64);
    }
    if (g == 0) {
        float4 o0, o1;
        o0.x = acc[0] > 0.f ? acc[0] : expf(acc[0]) - 1.f;
        o0.y = acc[1] > 0.f ? acc[1] : expf(acc[1]) - 1.f;
        o0.z = acc[2] > 0.f ? acc[2] : expf(acc[2]) - 1.f;
        o0.w = acc[3] > 0.f ? acc[3] : expf(acc[3]) - 1.f;
        o1.x = acc[4] > 0.f ? acc[4] : expf(acc[4]) - 1.f;
        o1.y = acc[5] > 0.f ? acc[5] : expf(acc[5]) - 1.f;
        o1.z = acc[6] > 0.f ? acc[6] : expf(acc[6]) - 1.f;
        o1.w = acc[7] > 0.f ? acc[7] : expf(acc[7]) - 1.f;
        float4* o4 = (float4*)out + (size_t)node * 16;
        o4[r * 2]     = o0;
        o4[r * 2 + 1] = o1;
    }
}

extern "C" void kernel_launch(void* const* d_in, const int* in_sizes, int n_in,
                              void* d_out, int out_size, void* d_ws, size_t ws_size,
                              hipStream_t stream) {
    const float* X  = (const float*)d_in[0];   // [N,128]
    const int*   ei = (const int*)d_in[1];     // [2,E]
    const float* W  = (const float*)d_in[2];   // [64,128]
    const float* a  = (const float*)d_in[3];   // [1,128]
    float* out = (float*)d_out;                // [N,64]

    const int N = in_sizes[0] / 128;
    const int E = in_sizes[1] / 2;
    const int nb = (N + 63) >> 6;              // buckets of 64 nodes

    char* p = (char*)d_ws;
    unsigned short* hb = (unsigned short*)p; p += (size_t)N * 64 * sizeof(unsigned short);
    uint4* Wbf    = (uint4*)p;  p += 1024 * sizeof(uint4);
    float* w_s    = (float*)p;  p += 128 * sizeof(float);
    float* w_t    = (float*)p;  p += 128 * sizeof(float);
    float* s_src  = (float*)p;  p += (size_t)N * sizeof(float);
    float* s_tgt  = (float*)p;  p += (size_t)N * sizeof(float);
    int*   deg    = (int*)p;    p += (size_t)N * sizeof(int);
    int*   base   = (int*)p;    p += (size_t)N * sizeof(int);
    int*   bcount = (int*)p;    p += (size_t)(nb + 64) * 16 * sizeof(int);  // padded
    int*   bcur   = (int*)p;    p += (size_t)(nb + 64) * 16 * sizeof(int);  // padded
    int*   bstart = (int*)p;    p += (size_t)(nb + 1) * sizeof(int);
    int*   csr_src= (int*)p;    p += (size_t)E * sizeof(int);
    int2*  st     = (int2*)p;

    hipMemsetAsync(bcount, 0, (size_t)nb * 16 * sizeof(int), stream);

    const int nstripes = (N + 15) / 16;
    k_prep  <<<17, 256, 0, stream>>>(W, a, Wbf, w_s, w_t);
    k_aux   <<<1280, 256, 0, stream>>>(X, ei, w_s, w_t, bcount, s_src, s_tgt, N, E);
    k_gemm  <<<(nstripes + 3) / 4, 256, 0, stream>>>(X, Wbf, hb, N, nstripes);
    k_bscan <<<1, 256, 0, stream>>>(bcount, bstart, bcur, nb, E);
    k_bucket<<<(E + 255) / 256, 256, 0, stream>>>(ei, bcur, st, E);
    k_local <<<nb, 256, 0, stream>>>(st, bstart, base, deg, csr_src, N);
    k_node  <<<(N + 3) / 4, 256, 0, stream>>>(base, deg, csr_src, s_src, s_tgt, hb, out, N);
}

// Round 9
// 146.704 us; speedup vs baseline: 1.8166x; 1.5106x over previous
//
#include <hip/hip_runtime.h>
#include <math.h>

#define ALPHA_LEAKY 0.2f
#define EPS_F 1e-10f
#define NBMAX 1024   // max buckets supported (N <= 65536)

typedef __attribute__((ext_vector_type(8))) short short8;   // 8 bf16 (4 VGPRs)
typedef __attribute__((ext_vector_type(4))) float f32x4;    // MFMA C/D frag

__device__ __forceinline__ unsigned short bf16_rne(float f) {
    unsigned u = __float_as_uint(f);
    u += 0x7FFFu + ((u >> 16) & 1u);
    return (unsigned short)(u >> 16);
}

// prep: W -> MFMA B-frags (bf16)
__global__ void k_prep(const float* __restrict__ W, uint4* __restrict__ Wbf) {
    int f = blockIdx.x * 256 + threadIdx.x;
    int nt = f >> 8;
    if (nt >= 4) return;                  // 1024 valid frags
    int l = f & 63, kt = (f >> 6) & 3;
    int nn = nt * 16 + (l & 15);
    int k  = kt * 32 + (l >> 4) * 8;
    const float* wr = W + nn * 128 + k;
    unsigned short b[8];
    #pragma unroll
    for (int j = 0; j < 8; ++j) b[j] = bf16_rne(wr[j]);
    uint4 v;
    v.x = (unsigned)b[0] | ((unsigned)b[1] << 16);
    v.y = (unsigned)b[2] | ((unsigned)b[3] << 16);
    v.z = (unsigned)b[4] | ((unsigned)b[5] << 16);
    v.w = (unsigned)b[6] | ((unsigned)b[7] << 16);
    Wbf[f] = v;
}

// MFMA GEMM + fused scores. One wave per 16-row stripe; W pinned as B-frags
// in 64 VGPRs; A-frags straight from fp32 X; no LDS.
// C/D map: col = lane&15 (ml), row = (lane>>4)*4 + reg.
// Scores from fp32 accumulators: s_src[row] = sum_col acc*a[col], reduced
// across the 16-lane ml group (shfl_xor 1,2,4,8 stays inside the group).
__global__ __launch_bounds__(256) void k_gemm(
    const float* __restrict__ X, const uint4* __restrict__ Wbf,
    const float* __restrict__ a, unsigned short* __restrict__ hb,
    float* __restrict__ s_src, float* __restrict__ s_tgt, int n, int nstripes) {
    const int lane = threadIdx.x & 63;
    const int ml = lane & 15, g = lane >> 4;
    short8 bfr[4][4];
    #pragma unroll
    for (int nt = 0; nt < 4; ++nt)
        #pragma unroll
        for (int kt = 0; kt < 4; ++kt) {
            uint4 v = Wbf[(nt * 4 + kt) * 64 + lane];
            bfr[nt][kt] = *(short8*)&v;
        }
    float as[4], at[4];
    #pragma unroll
    for (int nt = 0; nt < 4; ++nt) {
        as[nt] = a[nt * 16 + ml];
        at[nt] = a[64 + nt * 16 + ml];
    }
    for (int stripe = blockIdx.x * 4 + (threadIdx.x >> 6); stripe < nstripes;
         stripe += gridDim.x * 4) {
        const int row0 = stripe * 16;
        const int rrow = min(row0 + ml, n - 1);
        const float* xr = X + (size_t)rrow * 128;
        f32x4 acc[4] = {{0.f,0.f,0.f,0.f},{0.f,0.f,0.f,0.f},
                        {0.f,0.f,0.f,0.f},{0.f,0.f,0.f,0.f}};
        #pragma unroll
        for (int kt = 0; kt < 4; ++kt) {
            float4 x0 = *(const float4*)(xr + kt * 32 + g * 8);
            float4 x1 = *(const float4*)(xr + kt * 32 + g * 8 + 4);
            short8 af;
            af[0] = (short)bf16_rne(x0.x); af[1] = (short)bf16_rne(x0.y);
            af[2] = (short)bf16_rne(x0.z); af[3] = (short)bf16_rne(x0.w);
            af[4] = (short)bf16_rne(x1.x); af[5] = (short)bf16_rne(x1.y);
            af[6] = (short)bf16_rne(x1.z); af[7] = (short)bf16_rne(x1.w);
            #pragma unroll
            for (int nt = 0; nt < 4; ++nt)
                acc[nt] = __builtin_amdgcn_mfma_f32_16x16x32_bf16(
                    af, bfr[nt][kt], acc[nt], 0, 0, 0);
        }
        #pragma unroll
        for (int reg = 0; reg < 4; ++reg) {
            int row = row0 + g * 4 + reg;
            float p = acc[0][reg] * as[0] + acc[1][reg] * as[1] +
                      acc[2][reg] * as[2] + acc[3][reg] * as[3];
            float q = acc[0][reg] * at[0] + acc[1][reg] * at[1] +
                      acc[2][reg] * at[2] + acc[3][reg] * at[3];
            #pragma unroll
            for (int off = 1; off < 16; off <<= 1) {
                p += __shfl_xor(p, off, 64);
                q += __shfl_xor(q, off, 64);
            }
            if (ml == 0 && row < n) { s_src[row] = p; s_tgt[row] = q; }
        }
        #pragma unroll
        for (int nt = 0; nt < 4; ++nt)
            #pragma unroll
            for (int reg = 0; reg < 4; ++reg) {
                int row = row0 + g * 4 + reg;
                if (row < n)
                    hb[(size_t)row * 64 + nt * 16 + ml] = bf16_rne(acc[nt][reg]);
            }
    }
}

// pass 1 of counting sort: per-block LDS histogram of bucket = tgt>>6.
// 256 blocks, identical chunking as k_place. Coalesced flush, no global atomics.
__global__ __launch_bounds__(256) void k_hist(
    const int* __restrict__ ei, int* __restrict__ histg, int nb, int E, int epb) {
    __shared__ int hist[NBMAX];
    const int t = threadIdx.x;
    for (int k = t; k < nb; k += 256) hist[k] = 0;
    __syncthreads();
    const int e0 = blockIdx.x * epb, e1 = min(e0 + epb, E);
    for (int e = e0 + t; e < e1; e += 256)
        atomicAdd(&hist[ei[E + e] >> 6], 1);
    __syncthreads();
    int* outp = histg + (size_t)blockIdx.x * nb;
    for (int k = t; k < nb; k += 256) outp[k] = hist[k];
}

// per-bucket exclusive scan over the 256 block counts (one block per bucket);
// writes exclusive prefixes back in place and the bucket total.
__global__ __launch_bounds__(256) void k_colscan(
    int* __restrict__ histg, int* __restrict__ btot, int nb) {
    __shared__ int wsum[4];
    const int bucket = blockIdx.x;
    const int t = threadIdx.x, lane = t & 63, w = t >> 6;
    int v = histg[(size_t)t * nb + bucket];
    int pre = v;
    #pragma unroll
    for (int off = 1; off < 64; off <<= 1) {
        int x = __shfl_up(pre, off, 64);
        if (lane >= off) pre += x;
    }
    if (lane == 63) wsum[w] = pre;
    __syncthreads();
    int wb = 0;
    for (int k = 0; k < w; ++k) wb += wsum[k];
    histg[(size_t)t * nb + bucket] = wb + pre - v;   // exclusive
    if (t == 255) btot[bucket] = wb + pre;
}

// single-block exclusive scan of bucket totals -> bstart (nb <= 1024)
__global__ __launch_bounds__(256) void k_bscan(
    const int* __restrict__ btot, int* __restrict__ bstart, int nb, int E) {
    __shared__ int wsum[4];
    int t = threadIdx.x;
    int lane = t & 63, w = t >> 6;
    int v[4]; int sum = 0;
    #pragma unroll
    for (int j = 0; j < 4; ++j) {
        int idx = t * 4 + j;
        v[j] = (idx < nb) ? btot[idx] : 0;
        sum += v[j];
    }
    int pre = sum;
    #pragma unroll
    for (int off = 1; off < 64; off <<= 1) {
        int x = __shfl_up(pre, off, 64);
        if (lane >= off) pre += x;
    }
    if (lane == 63) wsum[w] = pre;
    __syncthreads();
    int wbase = 0;
    for (int k = 0; k < w; ++k) wbase += wsum[k];
    int run = wbase + pre - sum;
    #pragma unroll
    for (int j = 0; j < 4; ++j) {
        int idx = t * 4 + j;
        if (idx < nb) bstart[idx] = run;
        run += v[j];
    }
    if (t == 255) bstart[nb] = E;
}

// pass 2: place (src,tgt) into bucket regions using LDS cursors seeded from
// the scanned per-(block,bucket) offsets. Zero global atomics.
__global__ __launch_bounds__(256) void k_place(
    const int* __restrict__ ei, const int* __restrict__ histg,
    const int* __restrict__ bstart, int2* __restrict__ st,
    int nb, int E, int epb) {
    __shared__ int cur[NBMAX];
    const int t = threadIdx.x;
    const int* my = histg + (size_t)blockIdx.x * nb;
    for (int k = t; k < nb; k += 256) cur[k] = bstart[k] + my[k];
    __syncthreads();
    const int e0 = blockIdx.x * epb, e1 = min(e0 + epb, E);
    for (int e = e0 + t; e < e1; e += 256) {
        int s  = ei[e];
        int tt = ei[E + e];
        int slot = atomicAdd(&cur[tt >> 6], 1);
        st[slot] = make_int2(s, tt);
    }
}

// per-bucket local sort: LDS histogram of the 64 nodes -> deterministic
// base/deg; LDS-cursor placement writes csr_src into a contiguous region.
__global__ __launch_bounds__(256) void k_local(
    const int2* __restrict__ st, const int* __restrict__ bstart,
    int* __restrict__ base, int* __restrict__ deg, int* __restrict__ csr_src,
    int n) {
    __shared__ int hist[64];
    __shared__ int nbase[64];
    const int b = blockIdx.x;
    const int n0 = b << 6;
    const int t = threadIdx.x;
    if (t < 64) hist[t] = 0;
    __syncthreads();
    const int s0 = bstart[b], s1 = bstart[b + 1];
    for (int i = s0 + t; i < s1; i += 256)
        atomicAdd(&hist[st[i].y - n0], 1);
    __syncthreads();
    if (t < 64) {
        int v = hist[t];
        int pre = v;
        #pragma unroll
        for (int off = 1; off < 64; off <<= 1) {
            int x = __shfl_up(pre, off, 64);
            if (t >= off) pre += x;
        }
        int bs = s0 + pre - v;       // exclusive
        nbase[t] = bs;
        if (n0 + t < n) { base[n0 + t] = bs; deg[n0 + t] = v; }
    }
    __syncthreads();
    if (t < 64) hist[t] = nbase[t];  // reuse as cursors
    __syncthreads();
    for (int i = s0 + t; i < s1; i += 256) {
        int2 e = st[i];
        int slot = atomicAdd(&hist[e.y - n0], 1);
        csr_src[slot] = e.x;
    }
}

// per-node softmax + aggregation + ELU (one wave per node; lane = (g,r);
// 8 edges per step, each group reads one 128 B bf16 row as uint4).
__device__ __forceinline__ void accum8(float acc[8], uint4 hv, float w) {
    unsigned u[4] = {hv.x, hv.y, hv.z, hv.w};
    #pragma unroll
    for (int i = 0; i < 4; ++i) {
        float lo = __uint_as_float(u[i] << 16);
        float hi = __uint_as_float(u[i] & 0xFFFF0000u);
        acc[2 * i]     = fmaf(w, lo, acc[2 * i]);
        acc[2 * i + 1] = fmaf(w, hi, acc[2 * i + 1]);
    }
}

__global__ __launch_bounds__(256) void k_node(
    const int* __restrict__ base, const int* __restrict__ deg,
    const int* __restrict__ csr_src, const float* __restrict__ s_src,
    const float* __restrict__ s_tgt, const unsigned short* __restrict__ hb,
    float* __restrict__ out, int n) {
    const int lane = threadIdx.x & 63;
    const int node = blockIdx.x * 4 + (threadIdx.x >> 6);
    if (node >= n) return;
    const int b = base[node];
    const int d = deg[node];
    const float st = s_tgt[node];
    const int g = lane >> 3, r = lane & 7;
    float acc[8] = {0.f, 0.f, 0.f, 0.f, 0.f, 0.f, 0.f, 0.f};

    if (d <= 64) {
        int src_l = 0; float w_l = 0.f, v = -INFINITY;
        if (lane < d) {
            src_l = csr_src[b + lane];
            float x = s_src[src_l] + st;
            v = (x > 0.f) ? x : ALPHA_LEAKY * x;
        }
        float m = v;
        #pragma unroll
        for (int off = 32; off > 0; off >>= 1) m = fmaxf(m, __shfl_xor(m, off, 64));
        float ex = (lane < d) ? expf(v - m) : 0.f;
        float sum = ex;
        #pragma unroll
        for (int off = 32; off > 0; off >>= 1) sum += __shfl_xor(sum, off, 64);
        w_l = ex * (1.f / (sum + EPS_F));
        for (int k = 0; k < d; k += 8) {
            int ke = k + g;
            int s   = __shfl(src_l, ke, 64);
            float w = __shfl(w_l,  ke, 64);
            uint4 hv = ((const uint4*)(hb + (size_t)s * 64))[r];
            accum8(acc, hv, w);
        }
    } else {
        float m = -INFINITY;
        for (int c = lane; c < d; c += 64) {
            float x = s_src[csr_src[b + c]] + st;
            x = (x > 0.f) ? x : ALPHA_LEAKY * x;
            m = fmaxf(m, x);
        }
        #pragma unroll
        for (int off = 32; off > 0; off >>= 1) m = fmaxf(m, __shfl_xor(m, off, 64));
        float sum = 0.f;
        for (int c = lane; c < d; c += 64) {
            float x = s_src[csr_src[b + c]] + st;
            x = (x > 0.f) ? x : ALPHA_LEAKY * x;
            sum += expf(x - m);
        }
        #pragma unroll
        for (int off = 32; off > 0; off >>= 1) sum += __shfl_xor(sum, off, 64);
        float inv = 1.f / (sum + EPS_F);
        for (int c0 = 0; c0 < d; c0 += 64) {
            int j = c0 + lane;
            int src_l = 0; float w_l = 0.f;
            if (j < d) {
                src_l = csr_src[b + j];
                float x = s_src[src_l] + st;
                x = (x > 0.f) ? x : ALPHA_LEAKY * x;
                w_l = expf(x - m) * inv;
            }
            int lim = min(64, d - c0);
            for (int k = 0; k < lim; k += 8) {
                int ke = k + g;
                int s   = __shfl(src_l, ke, 64);
                float w = __shfl(w_l,  ke, 64);
                uint4 hv = ((const uint4*)(hb + (size_t)s * 64))[r];
                accum8(acc, hv, w);
            }
        }
    }

    #pragma unroll
    for (int off = 8; off <= 32; off <<= 1) {
        #pragma unroll
        for (int j = 0; j < 8; ++j) acc[j] += __shfl_xor(acc[j], off, 64);
    }
    if (g == 0) {
        float4 o0, o1;
        o0.x = acc[0] > 0.f ? acc[0] : expf(acc[0]) - 1.f;
        o0.y = acc[1] > 0.f ? acc[1] : expf(acc[1]) - 1.f;
        o0.z = acc[2] > 0.f ? acc[2] : expf(acc[2]) - 1.f;
        o0.w = acc[3] > 0.f ? acc[3] : expf(acc[3]) - 1.f;
        o1.x = acc[4] > 0.f ? acc[4] : expf(acc[4]) - 1.f;
        o1.y = acc[5] > 0.f ? acc[5] : expf(acc[5]) - 1.f;
        o1.z = acc[6] > 0.f ? acc[6] : expf(acc[6]) - 1.f;
        o1.w = acc[7] > 0.f ? acc[7] : expf(acc[7]) - 1.f;
        float4* o4 = (float4*)out + (size_t)node * 16;
        o4[r * 2]     = o0;
        o4[r * 2 + 1] = o1;
    }
}

extern "C" void kernel_launch(void* const* d_in, const int* in_sizes, int n_in,
                              void* d_out, int out_size, void* d_ws, size_t ws_size,
                              hipStream_t stream) {
    const float* X  = (const float*)d_in[0];   // [N,128]
    const int*   ei = (const int*)d_in[1];     // [2,E]
    const float* W  = (const float*)d_in[2];   // [64,128]
    const float* a  = (const float*)d_in[3];   // [1,128]
    float* out = (float*)d_out;                // [N,64]

    const int N = in_sizes[0] / 128;
    const int E = in_sizes[1] / 2;
    const int nb = (N + 63) >> 6;              // buckets of 64 nodes (<=1024)
    const int NBLK = 256;                      // hist/place blocks (fixed)
    const int epb = (E + NBLK - 1) / NBLK;

    char* p = (char*)d_ws;
    unsigned short* hb = (unsigned short*)p; p += (size_t)N * 64 * sizeof(unsigned short);
    uint4* Wbf    = (uint4*)p;  p += 1024 * sizeof(uint4);
    float* s_src  = (float*)p;  p += (size_t)N * sizeof(float);
    float* s_tgt  = (float*)p;  p += (size_t)N * sizeof(float);
    int*   deg    = (int*)p;    p += (size_t)N * sizeof(int);
    int*   base   = (int*)p;    p += (size_t)N * sizeof(int);
    int*   histg  = (int*)p;    p += (size_t)NBLK * nb * sizeof(int);
    int*   btot   = (int*)p;    p += (size_t)nb * sizeof(int);
    int*   bstart = (int*)p;    p += (size_t)(nb + 1) * sizeof(int);
    int*   csr_src= (int*)p;    p += (size_t)E * sizeof(int);
    int2*  st     = (int2*)p;

    const int nstripes = (N + 15) / 16;
    k_prep   <<<4, 256, 0, stream>>>(W, Wbf);
    k_gemm   <<<(nstripes + 3) / 4, 256, 0, stream>>>(X, Wbf, a, hb, s_src, s_tgt, N, nstripes);
    k_hist   <<<NBLK, 256, 0, stream>>>(ei, histg, nb, E, epb);
    k_colscan<<<nb, 256, 0, stream>>>(histg, btot, nb);
    k_bscan  <<<1, 256, 0, stream>>>(btot, bstart, nb, E);
    k_place  <<<NBLK, 256, 0, stream>>>(ei, histg, bstart, st, nb, E, epb);
    k_local  <<<nb, 256, 0, stream>>>(st, bstart, base, deg, csr_src, N);
    k_node   <<<(N + 3) / 4, 256, 0, stream>>>(base, deg, csr_src, s_src, s_tgt, hb, out, N);
}